// Round 1
// baseline (477.934 us; speedup 1.0000x reference)
//
#include <hip/hip_runtime.h>
#include <hip/hip_bf16.h>
#include <math.h>

#define XN 262144
#define NPAIR (XN - 1)
#define BN 64
#define HD 256
#define KK 8
#define THRC 1e-6f

__device__ __forceinline__ float gelu_f(float x) {
    return 0.5f * x * (1.0f + erff(x * 0.70710678118654752440f));
}

// ---------------- Kernel 1: first-8 discontinuity selection (1 wave / row) ----
__global__ __launch_bounds__(64) void select_kernel(const float* __restrict__ x,
                                                    float* __restrict__ out,
                                                    float* __restrict__ ws_uLuR) {
    const int b = blockIdx.x;
    const float* d = x + (size_t)b * 2 * XN;
    const float* c = d + XN;
    const int lane = threadIdx.x;

    int idxs[KK];
    float vflag[KK];
    int found = 0;

    // Phase 1: first K valid (has_disc) indices, ascending == ascending fc
    for (int base = 0; base < NPAIR && found < KK; base += 64) {
        int i = base + lane;
        bool v = (i < NPAIR) && (fabsf(d[i] - d[i + 1]) > THRC);
        unsigned long long m = __ballot(v);
        while (m && found < KK) {
            int l = __ffsll(m) - 1;
            idxs[found] = base + l;
            vflag[found] = 1.0f;
            ++found;
            m &= (m - 1);
        }
    }
    // Phase 2 (rare): fill with first invalid indices (top_k tie-break on -inf)
    if (found < KK) {
        for (int base = 0; base < NPAIR && found < KK; base += 64) {
            int i = base + lane;
            bool v = (i < NPAIR) && !(fabsf(d[i] - d[i + 1]) > THRC);
            unsigned long long m = __ballot(v);
            while (m && found < KK) {
                int l = __ffsll(m) - 1;
                idxs[found] = base + l;
                vflag[found] = 0.0f;
                ++found;
                m &= (m - 1);
            }
        }
    }

    if (lane < KK) {
        int i = idxs[lane];
        float uL = d[i];
        float uR = d[i + 1];
        float fc = (c[i] + c[i + 1]) * 0.5f;
        float* o = out + b * 48;
        o[16 + lane] = uL;       // channel 2
        o[24 + lane] = uR;       // channel 3
        o[32 + lane] = fc;       // channel 4
        o[40 + lane] = vflag[lane]; // channel 5
        ws_uLuR[(b * KK + lane) * 2 + 0] = uL;
        ws_uLuR[(b * KK + lane) * 2 + 1] = uR;
    }
}

// ---------------- Kernel 2: discontinuity count (memory-bound scan) ----------
__global__ __launch_bounds__(256) void count_kernel(const float* __restrict__ x,
                                                    int* __restrict__ ws_cnt) {
    __shared__ int sred[4];
    const int b = blockIdx.x >> 5;   // 32 blocks per row
    const int p = blockIdx.x & 31;
    const float* row = x + (size_t)b * 2 * XN;
    const int tid = threadIdx.x;

    int cnt = 0;
    const int base0 = p * 8192;
#pragma unroll
    for (int it = 0; it < 8; ++it) {
        int e0 = base0 + ((it << 8) + tid) * 4;
        float4 f = *(const float4*)(row + e0);
        cnt += (fabsf(f.x - f.y) > THRC);
        cnt += (fabsf(f.y - f.z) > THRC);
        cnt += (fabsf(f.z - f.w) > THRC);
        if (e0 + 4 < XN) {
            float e = row[e0 + 4];
            cnt += (fabsf(f.w - e) > THRC);
        }
    }
#pragma unroll
    for (int off = 32; off > 0; off >>= 1) cnt += __shfl_down(cnt, off, 64);
    int lane = tid & 63, wave = tid >> 6;
    if (lane == 0) sred[wave] = cnt;
    __syncthreads();
    if (tid == 0) ws_cnt[b * 32 + p] = sred[0] + sred[1] + sred[2] + sred[3];
}

// ---------------- Kernel 3: fused speed-predictor MLP (+count finalize) ------
// 128 blocks x 256 threads; block = (row, half): 4 tokens per block.
__device__ __forceinline__ void ln_stats(const float h[4], float stat[4][2],
                                         float red[4][4][2], int tid) {
    float s[4], q[4];
#pragma unroll
    for (int j = 0; j < 4; ++j) { s[j] = h[j]; q[j] = h[j] * h[j]; }
#pragma unroll
    for (int off = 32; off > 0; off >>= 1) {
#pragma unroll
        for (int j = 0; j < 4; ++j) {
            s[j] += __shfl_down(s[j], off, 64);
            q[j] += __shfl_down(q[j], off, 64);
        }
    }
    int wave = tid >> 6, lane = tid & 63;
    if (lane == 0) {
#pragma unroll
        for (int j = 0; j < 4; ++j) { red[wave][j][0] = s[j]; red[wave][j][1] = q[j]; }
    }
    __syncthreads();
    if (tid < 4) {
        float ts = 0.0f, tq = 0.0f;
#pragma unroll
        for (int w = 0; w < 4; ++w) { ts += red[w][tid][0]; tq += red[w][tid][1]; }
        float mu = ts * (1.0f / 256.0f);
        float vr = tq * (1.0f / 256.0f) - mu * mu;
        stat[tid][0] = mu;
        stat[tid][1] = rsqrtf(vr + 1e-5f);
    }
    __syncthreads();
}

__global__ __launch_bounds__(256) void mlp_kernel(
    const float* __restrict__ ws_uLuR, const int* __restrict__ ws_cnt,
    const float* __restrict__ w_in, const float* __restrict__ b_in,
    const float* __restrict__ ln_in_g, const float* __restrict__ ln_in_b,
    const float* __restrict__ rb_ln_g, const float* __restrict__ rb_ln_b,
    const float* __restrict__ rb_w1, const float* __restrict__ rb_b1,
    const float* __restrict__ rb_w2, const float* __restrict__ rb_b2,
    const float* __restrict__ out_ln_g, const float* __restrict__ out_ln_b,
    const float* __restrict__ out_w1, const float* __restrict__ out_b1,
    const float* __restrict__ out_w2, const float* __restrict__ out_b2,
    float* __restrict__ out) {
    __shared__ float zs[4][HD];      // LN output (K=256 stage input)
    __shared__ float z2[4][2 * HD];  // gelu(w1) output (K=512 stage input)
    __shared__ float z3[4][HD / 2];  // gelu(out_w1) output
    __shared__ float red[4][4][2];
    __shared__ float stat[4][2];

    const int tid = threadIdx.x;
    const int bid = blockIdx.x;
    const int b = bid >> 1;
    const int half = bid & 1;
    const int t = tid;

    // finalize front_count for this row (one block per row does it)
    if (half == 0 && tid == 0) {
        int s = 0;
        for (int p = 0; p < 32; ++p) s += ws_cnt[b * 32 + p];
        out[3072 + b] = (float)s;
    }

    float h[4];
    // ---- input layer: feats @ w_in + b_in, LN, gelu ----
    {
        float fw[6];
#pragma unroll
        for (int f = 0; f < 6; ++f) fw[f] = w_in[f * HD + t];
        float bin = b_in[t];
#pragma unroll
        for (int j = 0; j < 4; ++j) {
            int tok = b * KK + half * 4 + j;
            float uL = ws_uLuR[tok * 2 + 0];
            float uR = ws_uLuR[tok * 2 + 1];
            float dd = uL - uR;
            float sg = (dd > 0.0f) ? 1.0f : ((dd < 0.0f) ? -1.0f : 0.0f);
            h[j] = bin + uL * fw[0] + uR * fw[1] + dd * fw[2] + fabsf(dd) * fw[3] +
                   (uL + uR) * 0.5f * fw[4] + sg * fw[5];
        }
        ln_stats(h, stat, red, tid);
        float g = ln_in_g[t], be = ln_in_b[t];
#pragma unroll
        for (int j = 0; j < 4; ++j)
            h[j] = gelu_f((h[j] - stat[j][0]) * stat[j][1] * g + be);
    }

    // ---- 3 residual blocks ----
    for (int i = 0; i < 3; ++i) {
        ln_stats(h, stat, red, tid);
        {
            float gg = rb_ln_g[i * HD + t], bb = rb_ln_b[i * HD + t];
#pragma unroll
            for (int j = 0; j < 4; ++j)
                zs[j][t] = (h[j] - stat[j][0]) * stat[j][1] * gg + bb;
        }
        __syncthreads();

        // w1: (256 x 512), thread t computes cols t and t+256 for 4 tokens
        const float* w1 = rb_w1 + (size_t)i * HD * 2 * HD;
        float a0[4], a1[4];
        {
            float c0 = rb_b1[i * 2 * HD + t], c1 = rb_b1[i * 2 * HD + t + HD];
#pragma unroll
            for (int j = 0; j < 4; ++j) { a0[j] = c0; a1[j] = c1; }
        }
        const float* wr = w1 + t;
        for (int k = 0; k < HD; k += 4) {
            float4 zx[4];
#pragma unroll
            for (int j = 0; j < 4; ++j) zx[j] = *(const float4*)&zs[j][k];
            float wA[4], wB[4];
#pragma unroll
            for (int kk = 0; kk < 4; ++kk) {
                wA[kk] = wr[(k + kk) * 2 * HD];
                wB[kk] = wr[(k + kk) * 2 * HD + HD];
            }
#pragma unroll
            for (int j = 0; j < 4; ++j) {
                a0[j] += zx[j].x * wA[0] + zx[j].y * wA[1] + zx[j].z * wA[2] + zx[j].w * wA[3];
                a1[j] += zx[j].x * wB[0] + zx[j].y * wB[1] + zx[j].z * wB[2] + zx[j].w * wB[3];
            }
        }
#pragma unroll
        for (int j = 0; j < 4; ++j) {
            z2[j][t] = gelu_f(a0[j]);
            z2[j][t + HD] = gelu_f(a1[j]);
        }
        __syncthreads();

        // w2: (512 x 256), thread t computes col t for 4 tokens; residual add
        const float* w2 = rb_w2 + (size_t)i * 2 * HD * HD;
        float a[4];
        {
            float c2 = rb_b2[i * HD + t];
#pragma unroll
            for (int j = 0; j < 4; ++j) a[j] = c2;
        }
        const float* wr2 = w2 + t;
        for (int k = 0; k < 2 * HD; k += 4) {
            float4 zx[4];
#pragma unroll
            for (int j = 0; j < 4; ++j) zx[j] = *(const float4*)&z2[j][k];
            float w[4];
#pragma unroll
            for (int kk = 0; kk < 4; ++kk) w[kk] = wr2[(k + kk) * HD];
#pragma unroll
            for (int j = 0; j < 4; ++j)
                a[j] += zx[j].x * w[0] + zx[j].y * w[1] + zx[j].z * w[2] + zx[j].w * w[3];
        }
#pragma unroll
        for (int j = 0; j < 4; ++j) h[j] += a[j];
        // ln_stats at top of next iteration provides the barrier before zs reuse
    }

    // ---- output head ----
    ln_stats(h, stat, red, tid);
    {
        float gg = out_ln_g[t], bb = out_ln_b[t];
#pragma unroll
        for (int j = 0; j < 4; ++j)
            zs[j][t] = (h[j] - stat[j][0]) * stat[j][1] * gg + bb;
    }
    __syncthreads();

    if (t < HD / 2) {
        float a[4];
        float c = out_b1[t];
#pragma unroll
        for (int j = 0; j < 4; ++j) a[j] = c;
        const float* wr = out_w1 + t;
        for (int k = 0; k < HD; k += 4) {
            float4 zx[4];
#pragma unroll
            for (int j = 0; j < 4; ++j) zx[j] = *(const float4*)&zs[j][k];
            float w[4];
#pragma unroll
            for (int kk = 0; kk < 4; ++kk) w[kk] = wr[(k + kk) * (HD / 2)];
#pragma unroll
            for (int j = 0; j < 4; ++j)
                a[j] += zx[j].x * w[0] + zx[j].y * w[1] + zx[j].z * w[2] + zx[j].w * w[3];
        }
#pragma unroll
        for (int j = 0; j < 4; ++j) z3[j][t] = gelu_f(a[j]);
    }
    __syncthreads();

    if (tid < 8) {
        int j = tid >> 1;   // token within this block
        int o = tid & 1;    // speed channel
        float s = out_b2[o];
        for (int k = 0; k < HD / 2; ++k) s += z3[j][k] * out_w2[k * 2 + o];
        out[b * 48 + o * 8 + half * 4 + j] = s;
    }
}

extern "C" void kernel_launch(void* const* d_in, const int* in_sizes, int n_in,
                              void* d_out, int out_size, void* d_ws, size_t ws_size,
                              hipStream_t stream) {
    const float* x        = (const float*)d_in[0];
    const float* w_in     = (const float*)d_in[1];
    const float* b_in     = (const float*)d_in[2];
    const float* ln_in_g  = (const float*)d_in[3];
    const float* ln_in_b  = (const float*)d_in[4];
    const float* rb_ln_g  = (const float*)d_in[5];
    const float* rb_ln_b  = (const float*)d_in[6];
    const float* rb_w1    = (const float*)d_in[7];
    const float* rb_b1    = (const float*)d_in[8];
    const float* rb_w2    = (const float*)d_in[9];
    const float* rb_b2    = (const float*)d_in[10];
    const float* out_ln_g = (const float*)d_in[11];
    const float* out_ln_b = (const float*)d_in[12];
    const float* out_w1   = (const float*)d_in[13];
    const float* out_b1   = (const float*)d_in[14];
    const float* out_w2   = (const float*)d_in[15];
    const float* out_b2   = (const float*)d_in[16];

    float* out = (float*)d_out;
    float* wsf = (float*)d_ws;           // [0..1024): uL/uR pairs (64*8*2)
    int* wsc = (int*)(wsf + 1024);       // [.. +2048): 64*32 partial counts

    select_kernel<<<BN, 64, 0, stream>>>(x, out, wsf);
    count_kernel<<<BN * 32, 256, 0, stream>>>(x, wsc);
    mlp_kernel<<<BN * 2, 256, 0, stream>>>(
        wsf, wsc, w_in, b_in, ln_in_g, ln_in_b, rb_ln_g, rb_ln_b,
        rb_w1, rb_b1, rb_w2, rb_b2, out_ln_g, out_ln_b,
        out_w1, out_b1, out_w2, out_b2, out);
}

// Round 2
// 270.823 us; speedup vs baseline: 1.7647x; 1.7647x over previous
//
#include <hip/hip_runtime.h>
#include <hip/hip_bf16.h>
#include <math.h>

#define XN 262144
#define NPAIR (XN - 1)
#define BN 64
#define HD 256
#define KK 8
#define THRC 1e-6f

__device__ __forceinline__ float gelu_f(float x) {
    return 0.5f * x * (1.0f + erff(x * 0.70710678118654752440f));
}

// ---------------- Kernel 1: first-8 discontinuity selection (1 wave / row) ----
__global__ __launch_bounds__(64) void select_kernel(const float* __restrict__ x,
                                                    float* __restrict__ out,
                                                    float* __restrict__ ws_uLuR) {
    const int b = blockIdx.x;
    const float* d = x + (size_t)b * 2 * XN;
    const float* c = d + XN;
    const int lane = threadIdx.x;

    int idxs[KK];
    float vflag[KK];
    int found = 0;

    for (int base = 0; base < NPAIR && found < KK; base += 64) {
        int i = base + lane;
        bool v = (i < NPAIR) && (fabsf(d[i] - d[i + 1]) > THRC);
        unsigned long long m = __ballot(v);
        while (m && found < KK) {
            int l = __ffsll(m) - 1;
            idxs[found] = base + l;
            vflag[found] = 1.0f;
            ++found;
            m &= (m - 1);
        }
    }
    if (found < KK) {
        for (int base = 0; base < NPAIR && found < KK; base += 64) {
            int i = base + lane;
            bool v = (i < NPAIR) && !(fabsf(d[i] - d[i + 1]) > THRC);
            unsigned long long m = __ballot(v);
            while (m && found < KK) {
                int l = __ffsll(m) - 1;
                idxs[found] = base + l;
                vflag[found] = 0.0f;
                ++found;
                m &= (m - 1);
            }
        }
    }

    if (lane < KK) {
        int i = idxs[lane];
        float uL = d[i];
        float uR = d[i + 1];
        float fc = (c[i] + c[i + 1]) * 0.5f;
        float* o = out + b * 48;
        o[16 + lane] = uL;
        o[24 + lane] = uR;
        o[32 + lane] = fc;
        o[40 + lane] = vflag[lane];
        ws_uLuR[(b * KK + lane) * 2 + 0] = uL;
        ws_uLuR[(b * KK + lane) * 2 + 1] = uR;
    }
}

// ---------------- Kernel 2: discontinuity count (memory-bound scan) ----------
__global__ __launch_bounds__(256) void count_kernel(const float* __restrict__ x,
                                                    int* __restrict__ ws_cnt) {
    __shared__ int sred[4];
    const int b = blockIdx.x >> 5;
    const int p = blockIdx.x & 31;
    const float* row = x + (size_t)b * 2 * XN;
    const int tid = threadIdx.x;

    int cnt = 0;
    const int base0 = p * 8192;
#pragma unroll
    for (int it = 0; it < 8; ++it) {
        int e0 = base0 + ((it << 8) + tid) * 4;
        float4 f = *(const float4*)(row + e0);
        cnt += (fabsf(f.x - f.y) > THRC);
        cnt += (fabsf(f.y - f.z) > THRC);
        cnt += (fabsf(f.z - f.w) > THRC);
        if (e0 + 4 < XN) {
            float e = row[e0 + 4];
            cnt += (fabsf(f.w - e) > THRC);
        }
    }
#pragma unroll
    for (int off = 32; off > 0; off >>= 1) cnt += __shfl_down(cnt, off, 64);
    int lane = tid & 63, wave = tid >> 6;
    if (lane == 0) sred[wave] = cnt;
    __syncthreads();
    if (tid == 0) ws_cnt[b * 32 + p] = sred[0] + sred[1] + sred[2] + sred[3];
}

// ---------------- Kernel 3: fused speed-predictor MLP ------------------------
// 128 blocks x 512 threads; block = (row, half): 4 tokens.
// Activations kept token-transposed in LDS as float4 (one value per token).
// GEMMs: thread = (4 output cols) x (K-slice); float4 weight loads; split-K
// partials reduced through LDS.

#define FMA4(acc, w4, zc)                    \
    acc.x = fmaf(w4.x, zc, acc.x);           \
    acc.y = fmaf(w4.y, zc, acc.y);           \
    acc.z = fmaf(w4.z, zc, acc.z);           \
    acc.w = fmaf(w4.w, zc, acc.w);

__global__ __launch_bounds__(512) void mlp_kernel(
    const float* __restrict__ ws_uLuR, const int* __restrict__ ws_cnt,
    const float* __restrict__ w_in, const float* __restrict__ b_in,
    const float* __restrict__ ln_in_g, const float* __restrict__ ln_in_b,
    const float* __restrict__ rb_ln_g, const float* __restrict__ rb_ln_b,
    const float* __restrict__ rb_w1, const float* __restrict__ rb_b1,
    const float* __restrict__ rb_w2, const float* __restrict__ rb_b2,
    const float* __restrict__ out_ln_g, const float* __restrict__ out_ln_b,
    const float* __restrict__ out_w1, const float* __restrict__ out_b1,
    const float* __restrict__ out_w2, const float* __restrict__ out_b2,
    float* __restrict__ out) {
    __shared__ float4 hsv[HD];       // h, token-transposed
    __shared__ float4 ztv[HD];       // LN output, token-transposed
    __shared__ float4 z2tv[2 * HD];  // gelu(w1 out), token-transposed
    __shared__ float4 z3tv[HD / 2];  // gelu(out_w1 out)
    __shared__ float part[8192];     // split-K partials (32 KB, reused)
    __shared__ float red[4][4][2];
    __shared__ float stat[4][2];
    __shared__ float fin[2][8];

    const int tid = threadIdx.x;
    const int bid = blockIdx.x;
    const int b = bid >> 1;
    const int half = bid & 1;

    if (half == 0 && tid == 0) {
        int s = 0;
        for (int p = 0; p < 32; ++p) s += ws_cnt[b * 32 + p];
        out[3072 + b] = (float)s;
    }

    const int wave = tid >> 6, lane = tid & 63;

    // ---- input layer: feats @ w_in + b_in -> hsv ----
    if (tid < HD) {
        const int c = tid;
        float fw[6];
#pragma unroll
        for (int f = 0; f < 6; ++f) fw[f] = w_in[f * HD + c];
        float bin = b_in[c];
        float4 hv;
        float* hvp = (float*)&hv;
#pragma unroll
        for (int j = 0; j < 4; ++j) {
            int tok = b * KK + half * 4 + j;
            float uL = ws_uLuR[tok * 2 + 0];
            float uR = ws_uLuR[tok * 2 + 1];
            float dd = uL - uR;
            float sg = (dd > 0.0f) ? 1.0f : ((dd < 0.0f) ? -1.0f : 0.0f);
            hvp[j] = bin + uL * fw[0] + uR * fw[1] + dd * fw[2] +
                     fabsf(dd) * fw[3] + (uL + uR) * 0.5f * fw[4] + sg * fw[5];
        }
        hsv[c] = hv;
    }
    __syncthreads();

    // ---- LN stats helper (inlined as lambda-style macro via loop) ----
    // computed for hsv; results in stat[j] = {mu, rsqrt}
#define LN_STATS()                                                            \
    do {                                                                      \
        if (tid < HD) {                                                       \
            float4 h4 = hsv[tid];                                             \
            float s[4] = {h4.x, h4.y, h4.z, h4.w};                            \
            float q[4] = {h4.x * h4.x, h4.y * h4.y, h4.z * h4.z, h4.w * h4.w};\
            for (int off = 32; off > 0; off >>= 1) {                          \
                _Pragma("unroll") for (int j = 0; j < 4; ++j) {               \
                    s[j] += __shfl_down(s[j], off, 64);                       \
                    q[j] += __shfl_down(q[j], off, 64);                       \
                }                                                             \
            }                                                                 \
            if (lane == 0) {                                                  \
                _Pragma("unroll") for (int j = 0; j < 4; ++j) {               \
                    red[wave][j][0] = s[j];                                   \
                    red[wave][j][1] = q[j];                                   \
                }                                                             \
            }                                                                 \
        }                                                                     \
        __syncthreads();                                                      \
        if (tid < 4) {                                                        \
            float ts = 0.0f, tq = 0.0f;                                       \
            _Pragma("unroll") for (int w = 0; w < 4; ++w) {                   \
                ts += red[w][tid][0];                                         \
                tq += red[w][tid][1];                                         \
            }                                                                 \
            float mu = ts * (1.0f / 256.0f);                                  \
            float vr = tq * (1.0f / 256.0f) - mu * mu;                        \
            stat[tid][0] = mu;                                                \
            stat[tid][1] = rsqrtf(vr + 1e-5f);                                \
        }                                                                     \
        __syncthreads();                                                      \
    } while (0)

    // input LN + gelu (applied in place to hsv)
    LN_STATS();
    if (tid < HD) {
        const int c = tid;
        float g = ln_in_g[c], be = ln_in_b[c];
        float4 hv = hsv[c];
        float* hvp = (float*)&hv;
#pragma unroll
        for (int j = 0; j < 4; ++j)
            hvp[j] = gelu_f((hvp[j] - stat[j][0]) * stat[j][1] * g + be);
        hsv[c] = hv;
    }
    __syncthreads();

    // ---- 3 residual blocks ----
    for (int i = 0; i < 3; ++i) {
        LN_STATS();
        if (tid < HD) {
            const int c = tid;
            float gg = rb_ln_g[i * HD + c], bb = rb_ln_b[i * HD + c];
            float4 hv = hsv[c], zv;
            float* hvp = (float*)&hv;
            float* zvp = (float*)&zv;
#pragma unroll
            for (int j = 0; j < 4; ++j)
                zvp[j] = (hvp[j] - stat[j][0]) * stat[j][1] * gg + bb;
            ztv[c] = zv;
        }
        __syncthreads();

        // w1: K=256 -> N=512. cg = 4 cols, kh = K-slice of 64.
        {
            const float* w1 = rb_w1 + (size_t)i * HD * 2 * HD;
            const int cg = tid & 127, kh = tid >> 7;
            const float* wp = w1 + (size_t)(kh * 64) * (2 * HD) + cg * 4;
            float4 a0 = {0, 0, 0, 0}, a1 = {0, 0, 0, 0}, a2 = {0, 0, 0, 0},
                   a3 = {0, 0, 0, 0};
#pragma unroll 8
            for (int k = 0; k < 64; ++k) {
                float4 w4 = *(const float4*)wp;
                wp += 2 * HD;
                float4 z4 = ztv[kh * 64 + k];
                FMA4(a0, w4, z4.x);
                FMA4(a1, w4, z4.y);
                FMA4(a2, w4, z4.z);
                FMA4(a3, w4, z4.w);
            }
            float* pp = part + (kh * 128 + cg) * 16;
            *(float4*)(pp + 0) = a0;
            *(float4*)(pp + 4) = a1;
            *(float4*)(pp + 8) = a2;
            *(float4*)(pp + 12) = a3;
        }
        __syncthreads();
        // reduce partials + bias + gelu -> z2tv
        {
            const int c2 = tid;
            const int cg = c2 >> 2, c = c2 & 3;
            float b1v = rb_b1[i * 2 * HD + c2];
            float4 zv;
            float* zvp = (float*)&zv;
#pragma unroll
            for (int j = 0; j < 4; ++j) {
                int o = cg * 16 + j * 4 + c;
                float v = b1v + part[o] + part[o + 2048] + part[o + 4096] +
                          part[o + 6144];
                zvp[j] = gelu_f(v);
            }
            z2tv[c2] = zv;
        }
        __syncthreads();

        // w2: K=512 -> N=256. cg2 = 4 cols, kh2 = K-slice of 64 (8 slices).
        {
            const float* w2 = rb_w2 + (size_t)i * 2 * HD * HD;
            const int cg2 = tid & 63, kh2 = tid >> 6;
            const float* wp = w2 + (size_t)(kh2 * 64) * HD + cg2 * 4;
            float4 a0 = {0, 0, 0, 0}, a1 = {0, 0, 0, 0}, a2 = {0, 0, 0, 0},
                   a3 = {0, 0, 0, 0};
#pragma unroll 8
            for (int k = 0; k < 64; ++k) {
                float4 w4 = *(const float4*)wp;
                wp += HD;
                float4 z4 = z2tv[kh2 * 64 + k];
                FMA4(a0, w4, z4.x);
                FMA4(a1, w4, z4.y);
                FMA4(a2, w4, z4.z);
                FMA4(a3, w4, z4.w);
            }
            float* pp = part + (kh2 * 64 + cg2) * 16;
            *(float4*)(pp + 0) = a0;
            *(float4*)(pp + 4) = a1;
            *(float4*)(pp + 8) = a2;
            *(float4*)(pp + 12) = a3;
        }
        __syncthreads();
        // reduce + bias + residual add into hsv
        if (tid < HD) {
            const int c2 = tid;
            const int cg2 = c2 >> 2, c = c2 & 3;
            float b2v = rb_b2[i * HD + c2];
            float4 hv = hsv[c2];
            float* hvp = (float*)&hv;
#pragma unroll
            for (int j = 0; j < 4; ++j) {
                int o = cg2 * 16 + j * 4 + c;
                float v = b2v;
#pragma unroll
                for (int kh = 0; kh < 8; ++kh) v += part[o + kh * 1024];
                hvp[j] += v;
            }
            hsv[c2] = hv;
        }
        __syncthreads();
    }

    // ---- output head ----
    LN_STATS();
    if (tid < HD) {
        const int c = tid;
        float gg = out_ln_g[c], bb = out_ln_b[c];
        float4 hv = hsv[c], zv;
        float* hvp = (float*)&hv;
        float* zvp = (float*)&zv;
#pragma unroll
        for (int j = 0; j < 4; ++j)
            zvp[j] = (hvp[j] - stat[j][0]) * stat[j][1] * gg + bb;
        ztv[c] = zv;
    }
    __syncthreads();

    // out_w1: K=256 -> N=128. cg3 = 4 cols (32 groups), kh3 = K-slice of 16.
    {
        const int cg3 = tid & 31, kh3 = tid >> 5;
        const float* wp = out_w1 + (size_t)(kh3 * 16) * (HD / 2) + cg3 * 4;
        float4 a0 = {0, 0, 0, 0}, a1 = {0, 0, 0, 0}, a2 = {0, 0, 0, 0},
               a3 = {0, 0, 0, 0};
#pragma unroll 4
        for (int k = 0; k < 16; ++k) {
            float4 w4 = *(const float4*)wp;
            wp += HD / 2;
            float4 z4 = ztv[kh3 * 16 + k];
            FMA4(a0, w4, z4.x);
            FMA4(a1, w4, z4.y);
            FMA4(a2, w4, z4.z);
            FMA4(a3, w4, z4.w);
        }
        float* pp = part + (kh3 * 32 + cg3) * 16;
        *(float4*)(pp + 0) = a0;
        *(float4*)(pp + 4) = a1;
        *(float4*)(pp + 8) = a2;
        *(float4*)(pp + 12) = a3;
    }
    __syncthreads();
    if (tid < HD / 2) {
        const int c2 = tid;
        const int cg3 = c2 >> 2, c = c2 & 3;
        float bv = out_b1[c2];
        float4 zv;
        float* zvp = (float*)&zv;
#pragma unroll
        for (int j = 0; j < 4; ++j) {
            int o = cg3 * 16 + j * 4 + c;
            float v = bv;
#pragma unroll
            for (int kh = 0; kh < 16; ++kh) v += part[o + kh * 512];
            zvp[j] = gelu_f(v);
        }
        z3tv[c2] = zv;
    }
    __syncthreads();

    // out_w2: K=128 -> N=2. 128 threads (2 waves), shuffle-reduce.
    if (tid < HD / 2) {
        float4 z = z3tv[tid];
        float w0 = out_w2[tid * 2 + 0];
        float w1v = out_w2[tid * 2 + 1];
        float p[8];
        p[0] = z.x * w0; p[1] = z.x * w1v;
        p[2] = z.y * w0; p[3] = z.y * w1v;
        p[4] = z.z * w0; p[5] = z.z * w1v;
        p[6] = z.w * w0; p[7] = z.w * w1v;
#pragma unroll
        for (int off = 32; off > 0; off >>= 1) {
#pragma unroll
            for (int u = 0; u < 8; ++u) p[u] += __shfl_down(p[u], off, 64);
        }
        if (lane == 0) {
#pragma unroll
            for (int u = 0; u < 8; ++u) fin[wave][u] = p[u];
        }
    }
    __syncthreads();
    if (tid < 8) {
        int j = tid >> 1;
        int o = tid & 1;
        float s = out_b2[o] + fin[0][tid] + fin[1][tid];
        out[b * 48 + o * 8 + half * 4 + j] = s;
    }
}

extern "C" void kernel_launch(void* const* d_in, const int* in_sizes, int n_in,
                              void* d_out, int out_size, void* d_ws, size_t ws_size,
                              hipStream_t stream) {
    const float* x        = (const float*)d_in[0];
    const float* w_in     = (const float*)d_in[1];
    const float* b_in     = (const float*)d_in[2];
    const float* ln_in_g  = (const float*)d_in[3];
    const float* ln_in_b  = (const float*)d_in[4];
    const float* rb_ln_g  = (const float*)d_in[5];
    const float* rb_ln_b  = (const float*)d_in[6];
    const float* rb_w1    = (const float*)d_in[7];
    const float* rb_b1    = (const float*)d_in[8];
    const float* rb_w2    = (const float*)d_in[9];
    const float* rb_b2    = (const float*)d_in[10];
    const float* out_ln_g = (const float*)d_in[11];
    const float* out_ln_b = (const float*)d_in[12];
    const float* out_w1   = (const float*)d_in[13];
    const float* out_b1   = (const float*)d_in[14];
    const float* out_w2   = (const float*)d_in[15];
    const float* out_b2   = (const float*)d_in[16];

    float* out = (float*)d_out;
    float* wsf = (float*)d_ws;           // [0..1024): uL/uR pairs
    int* wsc = (int*)(wsf + 1024);       // 64*32 partial counts

    select_kernel<<<BN, 64, 0, stream>>>(x, out, wsf);
    count_kernel<<<BN * 32, 256, 0, stream>>>(x, wsc);
    mlp_kernel<<<BN * 2, 512, 0, stream>>>(
        wsf, wsc, w_in, b_in, ln_in_g, ln_in_b, rb_ln_g, rb_ln_b,
        rb_w1, rb_b1, rb_w2, rb_b2, out_ln_g, out_ln_b,
        out_w1, out_b1, out_w2, out_b2, out);
}

// Round 3
// 260.135 us; speedup vs baseline: 1.8373x; 1.0411x over previous
//
#include <hip/hip_runtime.h>
#include <hip/hip_bf16.h>
#include <math.h>

#define XN 262144
#define NPAIR (XN - 1)
#define BN 64
#define HD 256
#define KK 8
#define THRC 1e-6f

__device__ __forceinline__ float gelu_f(float x) {
    return 0.5f * x * (1.0f + erff(x * 0.70710678118654752440f));
}

// ---------------- Kernel 1: fused count + first-8 select ---------------------
// grid = 64 rows x 16 slices, 256 threads. Slice p counts pairs with left end
// in [p*16384, p*16384+16384); p==0's wave 0 additionally does the select scan.
__global__ __launch_bounds__(256) void count_select_kernel(
    const float* __restrict__ x, float* __restrict__ out,
    float* __restrict__ ws_uLuR, int* __restrict__ ws_cnt) {
    __shared__ int sred[4];
    const int b = blockIdx.x >> 4;
    const int p = blockIdx.x & 15;
    const float* row = x + (size_t)b * 2 * XN;
    const int tid = threadIdx.x;
    const int lane = tid & 63, wave = tid >> 6;

    // ---- select (slice 0, wave 0 only) ----
    if (p == 0 && tid < 64) {
        const float* c = row + XN;
        int idxs[KK];
        float vflag[KK];
        int found = 0;
        for (int base = 0; base < NPAIR && found < KK; base += 64) {
            int i = base + lane;
            bool v = (i < NPAIR) && (fabsf(row[i] - row[i + 1]) > THRC);
            unsigned long long m = __ballot(v);
            while (m && found < KK) {
                int l = __ffsll(m) - 1;
                idxs[found] = base + l;
                vflag[found] = 1.0f;
                ++found;
                m &= (m - 1);
            }
        }
        if (found < KK) {
            for (int base = 0; base < NPAIR && found < KK; base += 64) {
                int i = base + lane;
                bool v = (i < NPAIR) && !(fabsf(row[i] - row[i + 1]) > THRC);
                unsigned long long m = __ballot(v);
                while (m && found < KK) {
                    int l = __ffsll(m) - 1;
                    idxs[found] = base + l;
                    vflag[found] = 0.0f;
                    ++found;
                    m &= (m - 1);
                }
            }
        }
        if (lane < KK) {
            int i = idxs[lane];
            float uL = row[i];
            float uR = row[i + 1];
            float fc = (c[i] + c[i + 1]) * 0.5f;
            float* o = out + b * 48;
            o[16 + lane] = uL;
            o[24 + lane] = uR;
            o[32 + lane] = fc;
            o[40 + lane] = vflag[lane];
            ws_uLuR[(b * KK + lane) * 2 + 0] = uL;
            ws_uLuR[(b * KK + lane) * 2 + 1] = uR;
        }
    }

    // ---- count: 16384 left-ends per slice, 64 elems (16 float4) per thread --
    int cnt = 0;
    const int base0 = p * 16384;
#pragma unroll
    for (int it = 0; it < 16; ++it) {
        int e0 = base0 + ((it << 8) + tid) * 4;
        float4 f = *(const float4*)(row + e0);
        cnt += (fabsf(f.x - f.y) > THRC);
        cnt += (fabsf(f.y - f.z) > THRC);
        cnt += (fabsf(f.z - f.w) > THRC);
        if (e0 + 4 < XN) {
            float e = row[e0 + 4];
            cnt += (fabsf(f.w - e) > THRC);
        }
    }
#pragma unroll
    for (int off = 32; off > 0; off >>= 1) cnt += __shfl_down(cnt, off, 64);
    if (lane == 0) sred[wave] = cnt;
    __syncthreads();
    if (tid == 0) ws_cnt[blockIdx.x] = sred[0] + sred[1] + sred[2] + sred[3];
}

// ---------------- Kernel 2: fused speed-predictor MLP ------------------------
// 256 blocks x 512 threads; block = (row b, sub): 2 tokens (sub*2, sub*2+1).
// Activations token-transposed in LDS as float2. Thread = 4 output cols x
// K-slice; float4 weight loads; split-K partials reduced through LDS.

#define FMA4x2(a0, a1, w4, z2v)              \
    a0.x = fmaf(w4.x, z2v.x, a0.x);          \
    a0.y = fmaf(w4.y, z2v.x, a0.y);          \
    a0.z = fmaf(w4.z, z2v.x, a0.z);          \
    a0.w = fmaf(w4.w, z2v.x, a0.w);          \
    a1.x = fmaf(w4.x, z2v.y, a1.x);          \
    a1.y = fmaf(w4.y, z2v.y, a1.y);          \
    a1.z = fmaf(w4.z, z2v.y, a1.z);          \
    a1.w = fmaf(w4.w, z2v.y, a1.w);

__global__ __launch_bounds__(512) void mlp_kernel(
    const float* __restrict__ ws_uLuR, const int* __restrict__ ws_cnt,
    const float* __restrict__ w_in, const float* __restrict__ b_in,
    const float* __restrict__ ln_in_g, const float* __restrict__ ln_in_b,
    const float* __restrict__ rb_ln_g, const float* __restrict__ rb_ln_b,
    const float* __restrict__ rb_w1, const float* __restrict__ rb_b1,
    const float* __restrict__ rb_w2, const float* __restrict__ rb_b2,
    const float* __restrict__ out_ln_g, const float* __restrict__ out_ln_b,
    const float* __restrict__ out_w1, const float* __restrict__ out_b1,
    const float* __restrict__ out_w2, const float* __restrict__ out_b2,
    float* __restrict__ out) {
    __shared__ float2 hsv[HD];       // h, token-transposed (2 tokens)
    __shared__ float2 ztv[HD];       // LN output
    __shared__ float2 z2tv[2 * HD];  // gelu(w1 out)
    __shared__ float2 z3tv[HD / 2];  // gelu(out_w1 out)
    __shared__ float part[4096];     // split-K partials (16 KB)
    __shared__ float red[8][2][2];
    __shared__ float stat[2][2];
    __shared__ float fin[2][4];

    const int tid = threadIdx.x;
    const int bid = blockIdx.x;
    const int b = bid >> 2;
    const int sub = bid & 3;
    const int wave = tid >> 6, lane = tid & 63;

    // finalize front_count (sub==0, wave 0 lanes)
    if (sub == 0 && wave == 0) {
        int v = (lane < 16) ? ws_cnt[b * 16 + lane] : 0;
#pragma unroll
        for (int off = 8; off > 0; off >>= 1) v += __shfl_down(v, off, 64);
        if (lane == 0) out[3072 + b] = (float)v;
    }

    // ---- input layer: feats @ w_in + b_in -> hsv ----
    if (tid < HD) {
        const int c = tid;
        float fw[6];
#pragma unroll
        for (int f = 0; f < 6; ++f) fw[f] = w_in[f * HD + c];
        float bin = b_in[c];
        float2 hv;
        float* hvp = (float*)&hv;
#pragma unroll
        for (int j = 0; j < 2; ++j) {
            int tok = b * KK + sub * 2 + j;
            float uL = ws_uLuR[tok * 2 + 0];
            float uR = ws_uLuR[tok * 2 + 1];
            float dd = uL - uR;
            float sg = (dd > 0.0f) ? 1.0f : ((dd < 0.0f) ? -1.0f : 0.0f);
            hvp[j] = bin + uL * fw[0] + uR * fw[1] + dd * fw[2] +
                     fabsf(dd) * fw[3] + (uL + uR) * 0.5f * fw[4] + sg * fw[5];
        }
        hsv[c] = hv;
    }
    __syncthreads();

#define LN_STATS()                                                            \
    do {                                                                      \
        if (tid < HD) {                                                       \
            float2 h2 = hsv[tid];                                             \
            float s[2] = {h2.x, h2.y};                                        \
            float q[2] = {h2.x * h2.x, h2.y * h2.y};                          \
            for (int off = 32; off > 0; off >>= 1) {                          \
                _Pragma("unroll") for (int j = 0; j < 2; ++j) {               \
                    s[j] += __shfl_down(s[j], off, 64);                       \
                    q[j] += __shfl_down(q[j], off, 64);                       \
                }                                                             \
            }                                                                 \
            if (lane == 0) {                                                  \
                _Pragma("unroll") for (int j = 0; j < 2; ++j) {               \
                    red[wave][j][0] = s[j];                                   \
                    red[wave][j][1] = q[j];                                   \
                }                                                             \
            }                                                                 \
        }                                                                     \
        __syncthreads();                                                      \
        if (tid < 2) {                                                        \
            float ts = 0.0f, tq = 0.0f;                                       \
            _Pragma("unroll") for (int w = 0; w < 4; ++w) {                   \
                ts += red[w][tid][0];                                         \
                tq += red[w][tid][1];                                         \
            }                                                                 \
            float mu = ts * (1.0f / 256.0f);                                  \
            float vr = tq * (1.0f / 256.0f) - mu * mu;                        \
            stat[tid][0] = mu;                                                \
            stat[tid][1] = rsqrtf(vr + 1e-5f);                                \
        }                                                                     \
        __syncthreads();                                                      \
    } while (0)

    // input LN + gelu
    LN_STATS();
    if (tid < HD) {
        const int c = tid;
        float g = ln_in_g[c], be = ln_in_b[c];
        float2 hv = hsv[c];
        hv.x = gelu_f((hv.x - stat[0][0]) * stat[0][1] * g + be);
        hv.y = gelu_f((hv.y - stat[1][0]) * stat[1][1] * g + be);
        hsv[c] = hv;
    }
    __syncthreads();

    // ---- 3 residual blocks ----
    for (int i = 0; i < 3; ++i) {
        LN_STATS();
        if (tid < HD) {
            const int c = tid;
            float gg = rb_ln_g[i * HD + c], bb = rb_ln_b[i * HD + c];
            float2 hv = hsv[c], zv;
            zv.x = (hv.x - stat[0][0]) * stat[0][1] * gg + bb;
            zv.y = (hv.y - stat[1][0]) * stat[1][1] * gg + bb;
            ztv[c] = zv;
        }
        __syncthreads();

        // w1: K=256 -> N=512. cg = 4 cols (128 groups), kh = K-slice of 64 (4).
        {
            const float* w1 = rb_w1 + (size_t)i * HD * 2 * HD;
            const int cg = tid & 127, kh = tid >> 7;
            const float* wp = w1 + (size_t)(kh * 64) * (2 * HD) + cg * 4;
            float4 a0 = {0, 0, 0, 0}, a1 = {0, 0, 0, 0};
#pragma unroll 8
            for (int k = 0; k < 64; ++k) {
                float4 w4 = *(const float4*)wp;
                wp += 2 * HD;
                float2 z2v = ztv[kh * 64 + k];
                FMA4x2(a0, a1, w4, z2v);
            }
            float* pp = part + (kh * 128 + cg) * 8;
            *(float4*)(pp + 0) = a0;
            *(float4*)(pp + 4) = a1;
        }
        __syncthreads();
        // reduce partials + bias + gelu -> z2tv
        {
            const int c2 = tid;
            const int cg = c2 >> 2, c = c2 & 3;
            float b1v = rb_b1[i * 2 * HD + c2];
            float2 zv;
#pragma unroll
            for (int j = 0; j < 2; ++j) {
                int o = cg * 8 + j * 4 + c;
                float v = b1v + part[o] + part[o + 1024] + part[o + 2048] +
                          part[o + 3072];
                ((float*)&zv)[j] = gelu_f(v);
            }
            z2tv[c2] = zv;
        }
        __syncthreads();

        // w2: K=512 -> N=256. cg2 = 4 cols (64 groups), kh2 = K-slice of 64 (8).
        {
            const float* w2 = rb_w2 + (size_t)i * 2 * HD * HD;
            const int cg2 = tid & 63, kh2 = tid >> 6;
            const float* wp = w2 + (size_t)(kh2 * 64) * HD + cg2 * 4;
            float4 a0 = {0, 0, 0, 0}, a1 = {0, 0, 0, 0};
#pragma unroll 8
            for (int k = 0; k < 64; ++k) {
                float4 w4 = *(const float4*)wp;
                wp += HD;
                float2 z2v = z2tv[kh2 * 64 + k];
                FMA4x2(a0, a1, w4, z2v);
            }
            float* pp = part + (kh2 * 64 + cg2) * 8;
            *(float4*)(pp + 0) = a0;
            *(float4*)(pp + 4) = a1;
        }
        __syncthreads();
        // reduce + bias + residual add into hsv
        if (tid < HD) {
            const int c2 = tid;
            const int cg2 = c2 >> 2, c = c2 & 3;
            float b2v = rb_b2[i * HD + c2];
            float2 hv = hsv[c2];
#pragma unroll
            for (int j = 0; j < 2; ++j) {
                int o = cg2 * 8 + j * 4 + c;
                float v = b2v;
#pragma unroll
                for (int kh = 0; kh < 8; ++kh) v += part[o + kh * 512];
                ((float*)&hv)[j] += v;
            }
            hsv[c2] = hv;
        }
        __syncthreads();
    }

    // ---- output head ----
    LN_STATS();
    if (tid < HD) {
        const int c = tid;
        float gg = out_ln_g[c], bb = out_ln_b[c];
        float2 hv = hsv[c], zv;
        zv.x = (hv.x - stat[0][0]) * stat[0][1] * gg + bb;
        zv.y = (hv.y - stat[1][0]) * stat[1][1] * gg + bb;
        ztv[c] = zv;
    }
    __syncthreads();

    // out_w1: K=256 -> N=128. cg3 = 4 cols (32 groups), kh3 = K-slice of 16.
    {
        const int cg3 = tid & 31, kh3 = tid >> 5;
        const float* wp = out_w1 + (size_t)(kh3 * 16) * (HD / 2) + cg3 * 4;
        float4 a0 = {0, 0, 0, 0}, a1 = {0, 0, 0, 0};
#pragma unroll 4
        for (int k = 0; k < 16; ++k) {
            float4 w4 = *(const float4*)wp;
            wp += HD / 2;
            float2 z2v = ztv[kh3 * 16 + k];
            FMA4x2(a0, a1, w4, z2v);
        }
        float* pp = part + (kh3 * 32 + cg3) * 8;
        *(float4*)(pp + 0) = a0;
        *(float4*)(pp + 4) = a1;
    }
    __syncthreads();
    if (tid < HD / 2) {
        const int c2 = tid;
        const int cg3 = c2 >> 2, c = c2 & 3;
        float bv = out_b1[c2];
        float2 zv;
#pragma unroll
        for (int j = 0; j < 2; ++j) {
            int o = cg3 * 8 + j * 4 + c;
            float v = bv;
#pragma unroll
            for (int kh = 0; kh < 16; ++kh) v += part[o + kh * 256];
            ((float*)&zv)[j] = gelu_f(v);
        }
        z3tv[c2] = zv;
    }
    __syncthreads();

    // out_w2: K=128 -> N=2. 2 waves, shuffle-reduce.
    if (tid < HD / 2) {
        float2 z = z3tv[tid];
        float w0 = out_w2[tid * 2 + 0];
        float w1v = out_w2[tid * 2 + 1];
        float p[4];
        p[0] = z.x * w0; p[1] = z.x * w1v;
        p[2] = z.y * w0; p[3] = z.y * w1v;
#pragma unroll
        for (int off = 32; off > 0; off >>= 1) {
#pragma unroll
            for (int u = 0; u < 4; ++u) p[u] += __shfl_down(p[u], off, 64);
        }
        if (lane == 0) {
#pragma unroll
            for (int u = 0; u < 4; ++u) fin[wave][u] = p[u];
        }
    }
    __syncthreads();
    if (tid < 4) {
        int j = tid >> 1;   // token within block
        int o = tid & 1;    // speed channel
        float s = out_b2[o] + fin[0][tid] + fin[1][tid];
        out[b * 48 + o * 8 + sub * 2 + j] = s;
    }
}

extern "C" void kernel_launch(void* const* d_in, const int* in_sizes, int n_in,
                              void* d_out, int out_size, void* d_ws, size_t ws_size,
                              hipStream_t stream) {
    const float* x        = (const float*)d_in[0];
    const float* w_in     = (const float*)d_in[1];
    const float* b_in     = (const float*)d_in[2];
    const float* ln_in_g  = (const float*)d_in[3];
    const float* ln_in_b  = (const float*)d_in[4];
    const float* rb_ln_g  = (const float*)d_in[5];
    const float* rb_ln_b  = (const float*)d_in[6];
    const float* rb_w1    = (const float*)d_in[7];
    const float* rb_b1    = (const float*)d_in[8];
    const float* rb_w2    = (const float*)d_in[9];
    const float* rb_b2    = (const float*)d_in[10];
    const float* out_ln_g = (const float*)d_in[11];
    const float* out_ln_b = (const float*)d_in[12];
    const float* out_w1   = (const float*)d_in[13];
    const float* out_b1   = (const float*)d_in[14];
    const float* out_w2   = (const float*)d_in[15];
    const float* out_b2   = (const float*)d_in[16];

    float* out = (float*)d_out;
    float* wsf = (float*)d_ws;           // [0..1024): uL/uR pairs
    int* wsc = (int*)(wsf + 1024);       // 1024 partial counts

    count_select_kernel<<<BN * 16, 256, 0, stream>>>(x, out, wsf, wsc);
    mlp_kernel<<<BN * 4, 512, 0, stream>>>(
        wsf, wsc, w_in, b_in, ln_in_g, ln_in_b, rb_ln_g, rb_ln_b,
        rb_w1, rb_b1, rb_w2, rb_b2, out_ln_g, out_ln_b,
        out_w1, out_b1, out_w2, out_b2, out);
}

// Round 4
// 245.705 us; speedup vs baseline: 1.9452x; 1.0587x over previous
//
#include <hip/hip_runtime.h>
#include <hip/hip_bf16.h>
#include <math.h>

#define XN 262144
#define NPAIR (XN - 1)
#define BN 64
#define HD 256
#define KK 8
#define THRC 1e-6f

__device__ __forceinline__ float gelu_f(float x) {
    return 0.5f * x * (1.0f + erff(x * 0.70710678118654752440f));
}

__device__ __forceinline__ unsigned short f2bf(float f) {
    unsigned int x = __float_as_uint(f);
    unsigned int r = (x + 0x7fffu + ((x >> 16) & 1u)) >> 16;  // RNE
    return (unsigned short)r;
}

// ---------------- Kernel 0: weights fp32 -> bf16 into workspace -------------
// bw layout (ushort): [0, 393216) rb_w1 | [393216, 786432) rb_w2 |
//                     [786432, 819200) out_w1. 102400 threads x 8 elements.
__global__ __launch_bounds__(256) void convert_kernel(
    const float* __restrict__ rb_w1, const float* __restrict__ rb_w2,
    const float* __restrict__ out_w1, unsigned short* __restrict__ bw) {
    int t = blockIdx.x * 256 + threadIdx.x;
    const float* s;
    if (t < 49152) s = rb_w1 + (size_t)t * 8;
    else if (t < 98304) s = rb_w2 + (size_t)(t - 49152) * 8;
    else s = out_w1 + (size_t)(t - 98304) * 8;
    float4 a = *(const float4*)s;
    float4 b = *(const float4*)(s + 4);
    union { unsigned short u[8]; uint4 v; } r;
    r.u[0] = f2bf(a.x); r.u[1] = f2bf(a.y); r.u[2] = f2bf(a.z); r.u[3] = f2bf(a.w);
    r.u[4] = f2bf(b.x); r.u[5] = f2bf(b.y); r.u[6] = f2bf(b.z); r.u[7] = f2bf(b.w);
    *(uint4*)(bw + (size_t)t * 8) = r.v;
}

// ---------------- Kernel 1: fused count + first-8 select ---------------------
__global__ __launch_bounds__(256) void count_select_kernel(
    const float* __restrict__ x, float* __restrict__ out,
    float* __restrict__ ws_uLuR, int* __restrict__ ws_cnt) {
    __shared__ int sred[4];
    const int b = blockIdx.x >> 4;
    const int p = blockIdx.x & 15;
    const float* row = x + (size_t)b * 2 * XN;
    const int tid = threadIdx.x;
    const int lane = tid & 63, wave = tid >> 6;

    if (p == 0 && tid < 64) {
        const float* c = row + XN;
        int idxs[KK];
        float vflag[KK];
        int found = 0;
        for (int base = 0; base < NPAIR && found < KK; base += 64) {
            int i = base + lane;
            bool v = (i < NPAIR) && (fabsf(row[i] - row[i + 1]) > THRC);
            unsigned long long m = __ballot(v);
            while (m && found < KK) {
                int l = __ffsll(m) - 1;
                idxs[found] = base + l;
                vflag[found] = 1.0f;
                ++found;
                m &= (m - 1);
            }
        }
        if (found < KK) {
            for (int base = 0; base < NPAIR && found < KK; base += 64) {
                int i = base + lane;
                bool v = (i < NPAIR) && !(fabsf(row[i] - row[i + 1]) > THRC);
                unsigned long long m = __ballot(v);
                while (m && found < KK) {
                    int l = __ffsll(m) - 1;
                    idxs[found] = base + l;
                    vflag[found] = 0.0f;
                    ++found;
                    m &= (m - 1);
                }
            }
        }
        if (lane < KK) {
            int i = idxs[lane];
            float uL = row[i];
            float uR = row[i + 1];
            float fc = (c[i] + c[i + 1]) * 0.5f;
            float* o = out + b * 48;
            o[16 + lane] = uL;
            o[24 + lane] = uR;
            o[32 + lane] = fc;
            o[40 + lane] = vflag[lane];
            ws_uLuR[(b * KK + lane) * 2 + 0] = uL;
            ws_uLuR[(b * KK + lane) * 2 + 1] = uR;
        }
    }

    int cnt = 0;
    const int base0 = p * 16384;
#pragma unroll
    for (int it = 0; it < 16; ++it) {
        int e0 = base0 + ((it << 8) + tid) * 4;
        float4 f = *(const float4*)(row + e0);
        cnt += (fabsf(f.x - f.y) > THRC);
        cnt += (fabsf(f.y - f.z) > THRC);
        cnt += (fabsf(f.z - f.w) > THRC);
        if (e0 + 4 < XN) {
            float e = row[e0 + 4];
            cnt += (fabsf(f.w - e) > THRC);
        }
    }
#pragma unroll
    for (int off = 32; off > 0; off >>= 1) cnt += __shfl_down(cnt, off, 64);
    if (lane == 0) sred[wave] = cnt;
    __syncthreads();
    if (tid == 0) ws_cnt[blockIdx.x] = sred[0] + sred[1] + sred[2] + sred[3];
}

// ---------------- Kernel 2: fused speed-predictor MLP (bf16 weights) ---------
// 256 blocks x 512 threads; block = (row b, sub): 2 tokens. Each uint4 weight
// load = 8 bf16 cols. Split-K partials in LDS.

// FMA 8 cols x 2 tokens from one uint4 of bf16 (cols base..base+7)
#define BF8_FMA(w, z)                                                        \
    do {                                                                     \
        float f0, f1;                                                        \
        f0 = __uint_as_float((w).x << 16);                                   \
        f1 = __uint_as_float((w).x & 0xffff0000u);                           \
        a0[0] = fmaf(f0, (z).x, a0[0]); a1[0] = fmaf(f0, (z).y, a1[0]);      \
        a0[1] = fmaf(f1, (z).x, a0[1]); a1[1] = fmaf(f1, (z).y, a1[1]);      \
        f0 = __uint_as_float((w).y << 16);                                   \
        f1 = __uint_as_float((w).y & 0xffff0000u);                           \
        a0[2] = fmaf(f0, (z).x, a0[2]); a1[2] = fmaf(f0, (z).y, a1[2]);      \
        a0[3] = fmaf(f1, (z).x, a0[3]); a1[3] = fmaf(f1, (z).y, a1[3]);      \
        f0 = __uint_as_float((w).z << 16);                                   \
        f1 = __uint_as_float((w).z & 0xffff0000u);                           \
        a0[4] = fmaf(f0, (z).x, a0[4]); a1[4] = fmaf(f0, (z).y, a1[4]);      \
        a0[5] = fmaf(f1, (z).x, a0[5]); a1[5] = fmaf(f1, (z).y, a1[5]);      \
        f0 = __uint_as_float((w).w << 16);                                   \
        f1 = __uint_as_float((w).w & 0xffff0000u);                           \
        a0[6] = fmaf(f0, (z).x, a0[6]); a1[6] = fmaf(f0, (z).y, a1[6]);      \
        a0[7] = fmaf(f1, (z).x, a0[7]); a1[7] = fmaf(f1, (z).y, a1[7]);      \
    } while (0)

__global__ __launch_bounds__(512) void mlp_kernel(
    const float* __restrict__ ws_uLuR, const int* __restrict__ ws_cnt,
    const unsigned short* __restrict__ bw,
    const float* __restrict__ w_in, const float* __restrict__ b_in,
    const float* __restrict__ ln_in_g, const float* __restrict__ ln_in_b,
    const float* __restrict__ rb_ln_g, const float* __restrict__ rb_ln_b,
    const float* __restrict__ rb_b1, const float* __restrict__ rb_b2,
    const float* __restrict__ out_ln_g, const float* __restrict__ out_ln_b,
    const float* __restrict__ out_b1,
    const float* __restrict__ out_w2, const float* __restrict__ out_b2,
    float* __restrict__ out) {
    __shared__ float2 hsv[HD];
    __shared__ float2 ztv[HD];
    __shared__ float2 z2tv[2 * HD];
    __shared__ float2 z3tv[HD / 2];
    __shared__ float part[8192];   // 32 KB split-K partials
    __shared__ float red[8][2][2];
    __shared__ float stat[2][2];
    __shared__ float fin[2][4];

    const int tid = threadIdx.x;
    const int bid = blockIdx.x;
    const int b = bid >> 2;
    const int sub = bid & 3;
    const int wave = tid >> 6, lane = tid & 63;

    if (sub == 0 && wave == 0) {
        int v = (lane < 16) ? ws_cnt[b * 16 + lane] : 0;
#pragma unroll
        for (int off = 8; off > 0; off >>= 1) v += __shfl_down(v, off, 64);
        if (lane == 0) out[3072 + b] = (float)v;
    }

    // ---- input layer ----
    if (tid < HD) {
        const int c = tid;
        float fw[6];
#pragma unroll
        for (int f = 0; f < 6; ++f) fw[f] = w_in[f * HD + c];
        float bin = b_in[c];
        float2 hv;
        float* hvp = (float*)&hv;
#pragma unroll
        for (int j = 0; j < 2; ++j) {
            int tok = b * KK + sub * 2 + j;
            float uL = ws_uLuR[tok * 2 + 0];
            float uR = ws_uLuR[tok * 2 + 1];
            float dd = uL - uR;
            float sg = (dd > 0.0f) ? 1.0f : ((dd < 0.0f) ? -1.0f : 0.0f);
            hvp[j] = bin + uL * fw[0] + uR * fw[1] + dd * fw[2] +
                     fabsf(dd) * fw[3] + (uL + uR) * 0.5f * fw[4] + sg * fw[5];
        }
        hsv[c] = hv;
    }
    __syncthreads();

#define LN_STATS()                                                            \
    do {                                                                      \
        if (tid < HD) {                                                       \
            float2 h2 = hsv[tid];                                             \
            float s[2] = {h2.x, h2.y};                                        \
            float q[2] = {h2.x * h2.x, h2.y * h2.y};                          \
            for (int off = 32; off > 0; off >>= 1) {                          \
                _Pragma("unroll") for (int j = 0; j < 2; ++j) {               \
                    s[j] += __shfl_down(s[j], off, 64);                       \
                    q[j] += __shfl_down(q[j], off, 64);                       \
                }                                                             \
            }                                                                 \
            if (lane == 0) {                                                  \
                _Pragma("unroll") for (int j = 0; j < 2; ++j) {               \
                    red[wave][j][0] = s[j];                                   \
                    red[wave][j][1] = q[j];                                   \
                }                                                             \
            }                                                                 \
        }                                                                     \
        __syncthreads();                                                      \
        if (tid < 2) {                                                        \
            float ts = 0.0f, tq = 0.0f;                                       \
            _Pragma("unroll") for (int w = 0; w < 4; ++w) {                   \
                ts += red[w][tid][0];                                         \
                tq += red[w][tid][1];                                         \
            }                                                                 \
            float mu = ts * (1.0f / 256.0f);                                  \
            float vr = tq * (1.0f / 256.0f) - mu * mu;                        \
            stat[tid][0] = mu;                                                \
            stat[tid][1] = rsqrtf(vr + 1e-5f);                                \
        }                                                                     \
        __syncthreads();                                                      \
    } while (0)

    LN_STATS();
    if (tid < HD) {
        const int c = tid;
        float g = ln_in_g[c], be = ln_in_b[c];
        float2 hv = hsv[c];
        hv.x = gelu_f((hv.x - stat[0][0]) * stat[0][1] * g + be);
        hv.y = gelu_f((hv.y - stat[1][0]) * stat[1][1] * g + be);
        hsv[c] = hv;
    }
    __syncthreads();

    // ---- 3 residual blocks ----
    for (int i = 0; i < 3; ++i) {
        LN_STATS();
        if (tid < HD) {
            const int c = tid;
            float gg = rb_ln_g[i * HD + c], bb = rb_ln_b[i * HD + c];
            float2 hv = hsv[c], zv;
            zv.x = (hv.x - stat[0][0]) * stat[0][1] * gg + bb;
            zv.y = (hv.y - stat[1][0]) * stat[1][1] * gg + bb;
            ztv[c] = zv;
        }
        __syncthreads();

        // w1 (bf16): K=256 -> N=512. kh = 8 slices x 32 rows; cg = 8 cols.
        {
            const unsigned short* w1 = bw + (size_t)i * (HD * 2 * HD);
            const int cg = tid & 63, kh = tid >> 6;
            const unsigned short* wp = w1 + (size_t)(kh * 32) * (2 * HD) + cg * 8;
            float a0[8] = {0, 0, 0, 0, 0, 0, 0, 0};
            float a1[8] = {0, 0, 0, 0, 0, 0, 0, 0};
#pragma unroll 8
            for (int k = 0; k < 32; ++k) {
                uint4 w = *(const uint4*)wp;
                wp += 2 * HD;
                float2 z = ztv[kh * 32 + k];
                BF8_FMA(w, z);
            }
            float* pp = part + (kh * 64 + cg) * 16;
#pragma unroll
            for (int u = 0; u < 8; ++u) {
                pp[u * 2] = a0[u];
                pp[u * 2 + 1] = a1[u];
            }
        }
        __syncthreads();
        {
            const int c2 = tid;
            const int cg = c2 >> 3, u = c2 & 7;
            float vx = rb_b1[i * 2 * HD + c2];
            float vy = vx;
#pragma unroll
            for (int kh = 0; kh < 8; ++kh) {
                const float* pp = part + (kh * 64 + cg) * 16 + u * 2;
                vx += pp[0];
                vy += pp[1];
            }
            float2 zv;
            zv.x = gelu_f(vx);
            zv.y = gelu_f(vy);
            z2tv[c2] = zv;
        }
        __syncthreads();

        // w2 (bf16): K=512 -> N=256. kh2 = 16 slices x 32 rows; cg2 = 8 cols.
        {
            const unsigned short* w2 = bw + 393216 + (size_t)i * (2 * HD * HD);
            const int cg2 = tid & 31, kh2 = tid >> 5;
            const unsigned short* wp = w2 + (size_t)(kh2 * 32) * HD + cg2 * 8;
            float a0[8] = {0, 0, 0, 0, 0, 0, 0, 0};
            float a1[8] = {0, 0, 0, 0, 0, 0, 0, 0};
#pragma unroll 8
            for (int k = 0; k < 32; ++k) {
                uint4 w = *(const uint4*)wp;
                wp += HD;
                float2 z = z2tv[kh2 * 32 + k];
                BF8_FMA(w, z);
            }
            float* pp = part + (kh2 * 32 + cg2) * 16;
#pragma unroll
            for (int u = 0; u < 8; ++u) {
                pp[u * 2] = a0[u];
                pp[u * 2 + 1] = a1[u];
            }
        }
        __syncthreads();
        if (tid < HD) {
            const int cg2 = tid >> 3, u = tid & 7;
            float vx = rb_b2[i * HD + tid];
            float vy = vx;
#pragma unroll
            for (int kh = 0; kh < 16; ++kh) {
                const float* pp = part + (kh * 32 + cg2) * 16 + u * 2;
                vx += pp[0];
                vy += pp[1];
            }
            float2 hv = hsv[tid];
            hv.x += vx;
            hv.y += vy;
            hsv[tid] = hv;
        }
        __syncthreads();
    }

    // ---- output head ----
    LN_STATS();
    if (tid < HD) {
        const int c = tid;
        float gg = out_ln_g[c], bb = out_ln_b[c];
        float2 hv = hsv[c], zv;
        zv.x = (hv.x - stat[0][0]) * stat[0][1] * gg + bb;
        zv.y = (hv.y - stat[1][0]) * stat[1][1] * gg + bb;
        ztv[c] = zv;
    }
    __syncthreads();

    // out_w1 (bf16): K=256 -> N=128. kh3 = 32 slices x 8 rows; cg3 = 8 cols.
    {
        const unsigned short* ow1 = bw + 786432;
        const int cg3 = tid & 15, kh3 = tid >> 4;
        const unsigned short* wp = ow1 + (size_t)(kh3 * 8) * (HD / 2) + cg3 * 8;
        float a0[8] = {0, 0, 0, 0, 0, 0, 0, 0};
        float a1[8] = {0, 0, 0, 0, 0, 0, 0, 0};
#pragma unroll
        for (int k = 0; k < 8; ++k) {
            uint4 w = *(const uint4*)wp;
            wp += HD / 2;
            float2 z = ztv[kh3 * 8 + k];
            BF8_FMA(w, z);
        }
        float* pp = part + (kh3 * 16 + cg3) * 16;
#pragma unroll
        for (int u = 0; u < 8; ++u) {
            pp[u * 2] = a0[u];
            pp[u * 2 + 1] = a1[u];
        }
    }
    __syncthreads();
    if (tid < HD / 2) {
        const int cg3 = tid >> 3, u = tid & 7;
        float vx = out_b1[tid];
        float vy = vx;
#pragma unroll
        for (int kh = 0; kh < 32; ++kh) {
            const float* pp = part + (kh * 16 + cg3) * 16 + u * 2;
            vx += pp[0];
            vy += pp[1];
        }
        float2 zv;
        zv.x = gelu_f(vx);
        zv.y = gelu_f(vy);
        z3tv[tid] = zv;
    }
    __syncthreads();

    // out_w2: K=128 -> N=2 (fp32, tiny)
    if (tid < HD / 2) {
        float2 z = z3tv[tid];
        float w0 = out_w2[tid * 2 + 0];
        float w1v = out_w2[tid * 2 + 1];
        float p[4];
        p[0] = z.x * w0; p[1] = z.x * w1v;
        p[2] = z.y * w0; p[3] = z.y * w1v;
#pragma unroll
        for (int off = 32; off > 0; off >>= 1) {
#pragma unroll
            for (int u = 0; u < 4; ++u) p[u] += __shfl_down(p[u], off, 64);
        }
        if (lane == 0) {
#pragma unroll
            for (int u = 0; u < 4; ++u) fin[wave][u] = p[u];
        }
    }
    __syncthreads();
    if (tid < 4) {
        int j = tid >> 1;
        int o = tid & 1;
        float s = out_b2[o] + fin[0][tid] + fin[1][tid];
        out[b * 48 + o * 8 + sub * 2 + j] = s;
    }
}

extern "C" void kernel_launch(void* const* d_in, const int* in_sizes, int n_in,
                              void* d_out, int out_size, void* d_ws, size_t ws_size,
                              hipStream_t stream) {
    const float* x        = (const float*)d_in[0];
    const float* w_in     = (const float*)d_in[1];
    const float* b_in     = (const float*)d_in[2];
    const float* ln_in_g  = (const float*)d_in[3];
    const float* ln_in_b  = (const float*)d_in[4];
    const float* rb_ln_g  = (const float*)d_in[5];
    const float* rb_ln_b  = (const float*)d_in[6];
    const float* rb_w1    = (const float*)d_in[7];
    const float* rb_b1    = (const float*)d_in[8];
    const float* rb_w2    = (const float*)d_in[9];
    const float* rb_b2    = (const float*)d_in[10];
    const float* out_ln_g = (const float*)d_in[11];
    const float* out_ln_b = (const float*)d_in[12];
    const float* out_w1   = (const float*)d_in[13];
    const float* out_b1   = (const float*)d_in[14];
    const float* out_w2   = (const float*)d_in[15];
    const float* out_b2   = (const float*)d_in[16];

    float* out = (float*)d_out;
    float* wsf = (float*)d_ws;                        // uLuR pairs [0..1024)
    int* wsc = (int*)(wsf + 1024);                    // 1024 partial counts
    unsigned short* bw = (unsigned short*)(wsf + 2048);  // bf16 weights (1.6 MB)

    convert_kernel<<<400, 256, 0, stream>>>(rb_w1, rb_w2, out_w1, bw);
    count_select_kernel<<<BN * 16, 256, 0, stream>>>(x, out, wsf, wsc);
    mlp_kernel<<<BN * 4, 512, 0, stream>>>(
        wsf, wsc, bw, w_in, b_in, ln_in_g, ln_in_b, rb_ln_g, rb_ln_b,
        rb_b1, rb_b2, out_ln_g, out_ln_b, out_b1, out_w2, out_b2, out);
}